// Round 1
// baseline (670.262 us; speedup 1.0000x reference)
//
#include <hip/hip_runtime.h>

#define FD 128   // feature dim (both layers)

// ---------------- CSR build ----------------

__global__ void zero_kernel(int* __restrict__ p, int n) {
    int i = blockIdx.x * blockDim.x + threadIdx.x;
    if (i < n) p[i] = 0;
}

__global__ void count_kernel(const int* __restrict__ dst, int* __restrict__ cnt, int E) {
    int e = blockIdx.x * blockDim.x + threadIdx.x;
    if (e < E) atomicAdd(&cnt[dst[e]], 1);
}

__global__ __launch_bounds__(1024) void scan_kernel(
        const int* __restrict__ cnt, int* __restrict__ rp, int* __restrict__ cur,
        float* __restrict__ dis, int N, int E) {
    __shared__ int sums[1024];
    int tid = threadIdx.x;
    int chunk = (N + 1023) >> 10;
    int beg = tid * chunk;
    int end = min(beg + chunk, N);
    int s = 0;
    for (int i = beg; i < end; ++i) s += cnt[i];
    sums[tid] = s;
    __syncthreads();
    // inclusive scan over per-thread sums (Hillis-Steele)
    for (int off = 1; off < 1024; off <<= 1) {
        int add = (tid >= off) ? sums[tid - off] : 0;
        __syncthreads();
        sums[tid] += add;
        __syncthreads();
    }
    int run = sums[tid] - s;  // exclusive prefix for this chunk
    for (int i = beg; i < end; ++i) {
        int c = cnt[i];
        rp[i] = run;
        cur[i] = run;
        dis[i] = 1.0f / sqrtf((float)(c + 1));  // deg includes self-loop
        run += c;
    }
    if (tid == 0) rp[N] = E;
}

__global__ void fill_kernel(const int* __restrict__ src, const int* __restrict__ dst,
                            int* __restrict__ cur, int* __restrict__ col, int E) {
    int e = blockIdx.x * blockDim.x + threadIdx.x;
    if (e < E) {
        int p = atomicAdd(&cur[dst[e]], 1);
        col[p] = src[e];
    }
}

// ---------------- fp32 GEMM: C[M x 128] = A[M x 128] @ W[128 x 128] ----------------
// BM=64 rows/block, BK=32, 256 threads, 8x4 micro-tile.

#define BM 64
#define BK 32

__global__ __launch_bounds__(256) void gemm_kernel(
        const float* __restrict__ A, const float* __restrict__ W,
        float* __restrict__ C, int M) {
    __shared__ float xs[BK][BM + 1];   // transposed A tile, +1 pad breaks staging conflicts
    __shared__ float ws[BK][FD];
    int tid = threadIdx.x;
    int tx = tid & 31;       // col group: cols tx*4 .. +3
    int ty = tid >> 5;       // row group: rows ty*8 .. +7
    int rowBase = blockIdx.x * BM;
    float acc[8][4] = {};

    for (int kk = 0; kk < FD; kk += BK) {
        // stage A tile: 64 rows x 32 k = 512 float4, 2 per thread, transposed store
        #pragma unroll
        for (int i = 0; i < 2; ++i) {
            int f = tid + i * 256;
            int r = f >> 3;             // 8 float4 per row
            int kq = (f & 7) * 4;
            int grow = rowBase + r;
            float4 v = make_float4(0.f, 0.f, 0.f, 0.f);
            if (grow < M) v = *(const float4*)&A[(size_t)grow * FD + kk + kq];
            xs[kq + 0][r] = v.x; xs[kq + 1][r] = v.y;
            xs[kq + 2][r] = v.z; xs[kq + 3][r] = v.w;
        }
        // stage W tile: 32 k x 128 = 1024 float4, 4 per thread
        #pragma unroll
        for (int i = 0; i < 4; ++i) {
            int f = tid + i * 256;
            int k = f >> 5;
            int c = (f & 31) * 4;
            *(float4*)&ws[k][c] = *(const float4*)&W[(size_t)(kk + k) * FD + c];
        }
        __syncthreads();
        #pragma unroll
        for (int k = 0; k < BK; ++k) {
            float4 a0 = *(float4*)&xs[k][ty * 8];
            float4 a1 = *(float4*)&xs[k][ty * 8 + 4];
            float4 b  = *(float4*)&ws[k][tx * 4];
            float ar[8] = {a0.x, a0.y, a0.z, a0.w, a1.x, a1.y, a1.z, a1.w};
            #pragma unroll
            for (int r = 0; r < 8; ++r) {
                acc[r][0] = fmaf(ar[r], b.x, acc[r][0]);
                acc[r][1] = fmaf(ar[r], b.y, acc[r][1]);
                acc[r][2] = fmaf(ar[r], b.z, acc[r][2]);
                acc[r][3] = fmaf(ar[r], b.w, acc[r][3]);
            }
        }
        __syncthreads();
    }
    int rowTop = rowBase + ty * 8;
    #pragma unroll
    for (int r = 0; r < 8; ++r) {
        int grow = rowTop + r;
        if (grow < M) {
            float4 o = make_float4(acc[r][0], acc[r][1], acc[r][2], acc[r][3]);
            *(float4*)&C[(size_t)grow * FD + tx * 4] = o;
        }
    }
}

// ---------------- CSR aggregation + bias + ReLU ----------------
// out[v] = relu( dis[v] * ( sum_{u in in(v)} dis[u]*h[u]  +  dis[v]*h[v] ) + b )
// 32 lanes x float4 per node, 8 nodes per 256-thread block.

__global__ __launch_bounds__(256) void agg_kernel(
        const float4* __restrict__ h, const float* __restrict__ dis,
        const int* __restrict__ rp, const int* __restrict__ col,
        const float4* __restrict__ bias, float4* __restrict__ out, int N) {
    int v = blockIdx.x * 8 + threadIdx.y;
    if (v >= N) return;
    int t = threadIdx.x;
    float dv = dis[v];
    size_t vb = (size_t)v * 32 + t;
    float4 hv = h[vb];
    float4 acc;
    acc.x = dv * hv.x; acc.y = dv * hv.y; acc.z = dv * hv.z; acc.w = dv * hv.w;
    int e = rp[v];
    int end = rp[v + 1];
    for (; e + 4 <= end; e += 4) {
        int u0 = col[e], u1 = col[e + 1], u2 = col[e + 2], u3 = col[e + 3];
        float d0 = dis[u0], d1 = dis[u1], d2 = dis[u2], d3 = dis[u3];
        float4 h0 = h[(size_t)u0 * 32 + t];
        float4 h1 = h[(size_t)u1 * 32 + t];
        float4 h2 = h[(size_t)u2 * 32 + t];
        float4 h3 = h[(size_t)u3 * 32 + t];
        acc.x = fmaf(d0, h0.x, acc.x); acc.y = fmaf(d0, h0.y, acc.y);
        acc.z = fmaf(d0, h0.z, acc.z); acc.w = fmaf(d0, h0.w, acc.w);
        acc.x = fmaf(d1, h1.x, acc.x); acc.y = fmaf(d1, h1.y, acc.y);
        acc.z = fmaf(d1, h1.z, acc.z); acc.w = fmaf(d1, h1.w, acc.w);
        acc.x = fmaf(d2, h2.x, acc.x); acc.y = fmaf(d2, h2.y, acc.y);
        acc.z = fmaf(d2, h2.z, acc.z); acc.w = fmaf(d2, h2.w, acc.w);
        acc.x = fmaf(d3, h3.x, acc.x); acc.y = fmaf(d3, h3.y, acc.y);
        acc.z = fmaf(d3, h3.z, acc.z); acc.w = fmaf(d3, h3.w, acc.w);
    }
    for (; e < end; ++e) {
        int u = col[e];
        float du = dis[u];
        float4 hu = h[(size_t)u * 32 + t];
        acc.x = fmaf(du, hu.x, acc.x); acc.y = fmaf(du, hu.y, acc.y);
        acc.z = fmaf(du, hu.z, acc.z); acc.w = fmaf(du, hu.w, acc.w);
    }
    float4 bb = bias[t];
    float4 r;
    r.x = fmaxf(fmaf(dv, acc.x, bb.x), 0.0f);
    r.y = fmaxf(fmaf(dv, acc.y, bb.y), 0.0f);
    r.z = fmaxf(fmaf(dv, acc.z, bb.z), 0.0f);
    r.w = fmaxf(fmaf(dv, acc.w, bb.w), 0.0f);
    out[vb] = r;
}

// ---------------- launch ----------------

extern "C" void kernel_launch(void* const* d_in, const int* in_sizes, int n_in,
                              void* d_out, int out_size, void* d_ws, size_t ws_size,
                              hipStream_t stream) {
    const float* x  = (const float*)d_in[0];
    const int*   ei = (const int*)d_in[1];   // [2, E] int32
    const float* W1 = (const float*)d_in[2];
    const float* b1 = (const float*)d_in[3];
    const float* W2 = (const float*)d_in[4];
    const float* b2 = (const float*)d_in[5];
    // d_in[6] = num_nodes (unused; derived from sizes)

    int N = in_sizes[0] / FD;
    int E = in_sizes[1] / 2;
    const int* src = ei;
    const int* dst = ei + E;

    // workspace carve-up (256B-aligned regions)
    char* base = (char*)d_ws;
    size_t off = 0;
    auto align256 = [](size_t v) { return (v + 255) & ~(size_t)255; };
    int*   cnt  = (int*)(base + off); off += align256((size_t)(N + 1) * 4);
    int*   rp   = (int*)(base + off); off += align256((size_t)(N + 1) * 4);
    int*   cur  = (int*)(base + off); off += align256((size_t)N * 4);
    float* dis  = (float*)(base + off); off += align256((size_t)N * 4);
    int*   col  = (int*)(base + off); off += align256((size_t)E * 4);
    float* hbuf = (float*)(base + off); off += align256((size_t)N * FD * 4);
    (void)ws_size; (void)n_in; (void)out_size;

    float* z1 = (float*)d_out;   // layer-1 output lives in d_out, then overwritten

    int tE = (E + 255) / 256;
    int tN = (N + 255) / 256;

    zero_kernel <<<tN, 256, 0, stream>>>(cnt, N);
    count_kernel<<<tE, 256, 0, stream>>>(dst, cnt, E);
    scan_kernel <<<1, 1024, 0, stream>>>(cnt, rp, cur, dis, N, E);
    fill_kernel <<<tE, 256, 0, stream>>>(src, dst, cur, col, E);

    dim3 aggBlk(32, 8);
    int aggGrid = (N + 7) / 8;
    int gemmGrid = (N + BM - 1) / BM;

    // layer 1: h = x @ W1 ; z1 = relu(agg(h) + b1)
    gemm_kernel<<<gemmGrid, 256, 0, stream>>>(x, W1, hbuf, N);
    agg_kernel <<<aggGrid, aggBlk, 0, stream>>>((const float4*)hbuf, dis, rp, col,
                                                (const float4*)b1, (float4*)z1, N);
    // layer 2: h = z1 @ W2 ; out = relu(agg(h) + b2)
    gemm_kernel<<<gemmGrid, 256, 0, stream>>>(z1, W2, hbuf, N);
    agg_kernel <<<aggGrid, aggBlk, 0, stream>>>((const float4*)hbuf, dis, rp, col,
                                                (const float4*)b2, (float4*)d_out, N);
}

// Round 2
// 540.339 us; speedup vs baseline: 1.2404x; 1.2404x over previous
//
#include <hip/hip_runtime.h>

#define FD 128   // feature dim (both layers)

// ---------------- CSR build ----------------

__global__ void count_kernel(const int* __restrict__ dst, int* __restrict__ cnt, int E) {
    int e = blockIdx.x * blockDim.x + threadIdx.x;
    if (e < E) atomicAdd(&cnt[dst[e]], 1);
}

// Phase 1: per-block (1024 elems) sums
__global__ __launch_bounds__(256) void scan_blocksums(
        const int* __restrict__ cnt, int* __restrict__ bsum, int N) {
    int base = blockIdx.x * 1024 + threadIdx.x * 4;
    int s = 0;
    if (base + 3 < N) {
        int4 c = *(const int4*)&cnt[base];
        s = c.x + c.y + c.z + c.w;
    } else {
        for (int i = base; i < N; ++i) s += cnt[i];
    }
    #pragma unroll
    for (int off = 32; off > 0; off >>= 1) s += __shfl_down(s, off);
    __shared__ int wsum[4];
    if ((threadIdx.x & 63) == 0) wsum[threadIdx.x >> 6] = s;
    __syncthreads();
    if (threadIdx.x == 0) bsum[blockIdx.x] = wsum[0] + wsum[1] + wsum[2] + wsum[3];
}

// Phase 2: exclusive scan of block sums (nb <= 256)
__global__ __launch_bounds__(256) void scan_offsets(
        const int* __restrict__ bsum, int* __restrict__ boff, int nb) {
    __shared__ int sm[256];
    int t = threadIdx.x;
    int v = (t < nb) ? bsum[t] : 0;
    sm[t] = v;
    __syncthreads();
    for (int off = 1; off < 256; off <<= 1) {
        int add = (t >= off) ? sm[t - off] : 0;
        __syncthreads();
        sm[t] += add;
        __syncthreads();
    }
    if (t < nb) boff[t] = sm[t] - v;
}

// Phase 3: recompute local scan, write rp/cur/dis
__global__ __launch_bounds__(256) void scan_write(
        const int* __restrict__ cnt, const int* __restrict__ boff,
        int* __restrict__ rp, int* __restrict__ cur, float* __restrict__ dis,
        int N, int E) {
    __shared__ int sm[256];
    int t = threadIdx.x;
    int base = blockIdx.x * 1024 + t * 4;
    int c[4] = {0, 0, 0, 0};
    bool full = (base + 3 < N);
    if (full) {
        int4 q = *(const int4*)&cnt[base];
        c[0] = q.x; c[1] = q.y; c[2] = q.z; c[3] = q.w;
    } else {
        for (int j = 0; j < 4; ++j) if (base + j < N) c[j] = cnt[base + j];
    }
    int s = c[0] + c[1] + c[2] + c[3];
    sm[t] = s;
    __syncthreads();
    for (int off = 1; off < 256; off <<= 1) {
        int add = (t >= off) ? sm[t - off] : 0;
        __syncthreads();
        sm[t] += add;
        __syncthreads();
    }
    int run = boff[blockIdx.x] + sm[t] - s;   // exclusive prefix for this thread
    int r[4]; float d[4];
    #pragma unroll
    for (int j = 0; j < 4; ++j) {
        r[j] = run;
        d[j] = 1.0f / sqrtf((float)(c[j] + 1));  // deg includes self-loop
        run += c[j];
    }
    if (full) {
        *(int4*)&rp[base]  = make_int4(r[0], r[1], r[2], r[3]);
        *(int4*)&cur[base] = make_int4(r[0], r[1], r[2], r[3]);
        *(float4*)&dis[base] = make_float4(d[0], d[1], d[2], d[3]);
    } else {
        for (int j = 0; j < 4; ++j) if (base + j < N) {
            rp[base + j] = r[j]; cur[base + j] = r[j]; dis[base + j] = d[j];
        }
    }
    if (blockIdx.x == 0 && t == 0) rp[N] = E;
}

__global__ void fill_kernel(const int* __restrict__ src, const int* __restrict__ dst,
                            int* __restrict__ cur, int* __restrict__ col, int E) {
    int e = blockIdx.x * blockDim.x + threadIdx.x;
    if (e < E) {
        int p = atomicAdd(&cur[dst[e]], 1);
        col[p] = src[e];
    }
}

// ---------------- fp32 GEMM: C[M x 128] = A[M x 128] @ W[128 x 128] ----------------
// BM=64 rows/block, BK=32, 256 threads, 8x4 micro-tile.

#define BM 64
#define BK 32

__global__ __launch_bounds__(256) void gemm_kernel(
        const float* __restrict__ A, const float* __restrict__ W,
        float* __restrict__ C, int M) {
    __shared__ float xs[BK][BM + 1];
    __shared__ float ws[BK][FD];
    int tid = threadIdx.x;
    int tx = tid & 31;
    int ty = tid >> 5;
    int rowBase = blockIdx.x * BM;
    float acc[8][4] = {};

    for (int kk = 0; kk < FD; kk += BK) {
        #pragma unroll
        for (int i = 0; i < 2; ++i) {
            int f = tid + i * 256;
            int r = f >> 3;
            int kq = (f & 7) * 4;
            int grow = rowBase + r;
            float4 v = make_float4(0.f, 0.f, 0.f, 0.f);
            if (grow < M) v = *(const float4*)&A[(size_t)grow * FD + kk + kq];
            xs[kq + 0][r] = v.x; xs[kq + 1][r] = v.y;
            xs[kq + 2][r] = v.z; xs[kq + 3][r] = v.w;
        }
        #pragma unroll
        for (int i = 0; i < 4; ++i) {
            int f = tid + i * 256;
            int k = f >> 5;
            int c = (f & 31) * 4;
            *(float4*)&ws[k][c] = *(const float4*)&W[(size_t)(kk + k) * FD + c];
        }
        __syncthreads();
        #pragma unroll
        for (int k = 0; k < BK; ++k) {
            float4 a0 = *(float4*)&xs[k][ty * 8];
            float4 a1 = *(float4*)&xs[k][ty * 8 + 4];
            float4 b  = *(float4*)&ws[k][tx * 4];
            float ar[8] = {a0.x, a0.y, a0.z, a0.w, a1.x, a1.y, a1.z, a1.w};
            #pragma unroll
            for (int r = 0; r < 8; ++r) {
                acc[r][0] = fmaf(ar[r], b.x, acc[r][0]);
                acc[r][1] = fmaf(ar[r], b.y, acc[r][1]);
                acc[r][2] = fmaf(ar[r], b.z, acc[r][2]);
                acc[r][3] = fmaf(ar[r], b.w, acc[r][3]);
            }
        }
        __syncthreads();
    }
    int rowTop = rowBase + ty * 8;
    #pragma unroll
    for (int r = 0; r < 8; ++r) {
        int grow = rowTop + r;
        if (grow < M) {
            float4 o = make_float4(acc[r][0], acc[r][1], acc[r][2], acc[r][3]);
            *(float4*)&C[(size_t)grow * FD + tx * 4] = o;
        }
    }
}

// ---------------- CSR aggregation + bias + ReLU ----------------
// One node per 64-lane wave; lane t holds features [2t, 2t+1] as float2.
// out[v] = relu( dis[v] * ( sum_u dis[u]*h[u] + dis[v]*h[v] ) + b )

__global__ __launch_bounds__(256) void agg_kernel(
        const float2* __restrict__ h, const float* __restrict__ dis,
        const int* __restrict__ rp, const int* __restrict__ col,
        const float2* __restrict__ bias, float2* __restrict__ out, int N) {
    int v = blockIdx.x * 4 + threadIdx.y;          // blockDim = (64, 4) → wave per node
    v = __builtin_amdgcn_readfirstlane(v);         // wave-uniform → scalar loads for rp/col
    if (v >= N) return;
    int t = threadIdx.x;                           // 0..63
    float dv = dis[v];
    size_t vb = (size_t)v * 64 + t;
    float2 hv = h[vb];
    float2 acc;
    acc.x = dv * hv.x; acc.y = dv * hv.y;
    int e = rp[v];
    int end = rp[v + 1];
    for (; e + 8 <= end; e += 8) {
        int   u0 = col[e],     u1 = col[e + 1], u2 = col[e + 2], u3 = col[e + 3];
        int   u4 = col[e + 4], u5 = col[e + 5], u6 = col[e + 6], u7 = col[e + 7];
        float d0 = dis[u0], d1 = dis[u1], d2 = dis[u2], d3 = dis[u3];
        float d4 = dis[u4], d5 = dis[u5], d6 = dis[u6], d7 = dis[u7];
        float2 h0 = h[(size_t)u0 * 64 + t];
        float2 h1 = h[(size_t)u1 * 64 + t];
        float2 h2 = h[(size_t)u2 * 64 + t];
        float2 h3 = h[(size_t)u3 * 64 + t];
        float2 h4 = h[(size_t)u4 * 64 + t];
        float2 h5 = h[(size_t)u5 * 64 + t];
        float2 h6 = h[(size_t)u6 * 64 + t];
        float2 h7 = h[(size_t)u7 * 64 + t];
        acc.x = fmaf(d0, h0.x, acc.x); acc.y = fmaf(d0, h0.y, acc.y);
        acc.x = fmaf(d1, h1.x, acc.x); acc.y = fmaf(d1, h1.y, acc.y);
        acc.x = fmaf(d2, h2.x, acc.x); acc.y = fmaf(d2, h2.y, acc.y);
        acc.x = fmaf(d3, h3.x, acc.x); acc.y = fmaf(d3, h3.y, acc.y);
        acc.x = fmaf(d4, h4.x, acc.x); acc.y = fmaf(d4, h4.y, acc.y);
        acc.x = fmaf(d5, h5.x, acc.x); acc.y = fmaf(d5, h5.y, acc.y);
        acc.x = fmaf(d6, h6.x, acc.x); acc.y = fmaf(d6, h6.y, acc.y);
        acc.x = fmaf(d7, h7.x, acc.x); acc.y = fmaf(d7, h7.y, acc.y);
    }
    for (; e < end; ++e) {
        int u = col[e];
        float du = dis[u];
        float2 hu = h[(size_t)u * 64 + t];
        acc.x = fmaf(du, hu.x, acc.x); acc.y = fmaf(du, hu.y, acc.y);
    }
    float2 bb = bias[t];
    float2 r;
    r.x = fmaxf(fmaf(dv, acc.x, bb.x), 0.0f);
    r.y = fmaxf(fmaf(dv, acc.y, bb.y), 0.0f);
    out[vb] = r;
}

// ---------------- launch ----------------

extern "C" void kernel_launch(void* const* d_in, const int* in_sizes, int n_in,
                              void* d_out, int out_size, void* d_ws, size_t ws_size,
                              hipStream_t stream) {
    const float* x  = (const float*)d_in[0];
    const int*   ei = (const int*)d_in[1];   // [2, E] int32
    const float* W1 = (const float*)d_in[2];
    const float* b1 = (const float*)d_in[3];
    const float* W2 = (const float*)d_in[4];
    const float* b2 = (const float*)d_in[5];

    int N = in_sizes[0] / FD;
    int E = in_sizes[1] / 2;
    const int* src = ei;
    const int* dst = ei + E;

    char* base = (char*)d_ws;
    size_t off = 0;
    auto align256 = [](size_t v) { return (v + 255) & ~(size_t)255; };
    int*   cnt  = (int*)(base + off); off += align256((size_t)(N + 1) * 4);
    int*   rp   = (int*)(base + off); off += align256((size_t)(N + 1) * 4);
    int*   cur  = (int*)(base + off); off += align256((size_t)N * 4);
    float* dis  = (float*)(base + off); off += align256((size_t)N * 4);
    int*   bsum = (int*)(base + off); off += align256(256 * 4);
    int*   boff = (int*)(base + off); off += align256(256 * 4);
    int*   col  = (int*)(base + off); off += align256((size_t)E * 4);
    float* hbuf = (float*)(base + off); off += align256((size_t)N * FD * 4);
    (void)ws_size; (void)n_in; (void)out_size;

    float* z1 = (float*)d_out;

    int tE = (E + 255) / 256;
    int nb = (N + 1023) / 1024;   // blocks for scan phases (<= 256)

    hipMemsetAsync(cnt, 0, (size_t)N * 4, stream);
    count_kernel   <<<tE, 256, 0, stream>>>(dst, cnt, E);
    scan_blocksums <<<nb, 256, 0, stream>>>(cnt, bsum, N);
    scan_offsets   <<<1, 256, 0, stream>>>(bsum, boff, nb);
    scan_write     <<<nb, 256, 0, stream>>>(cnt, boff, rp, cur, dis, N, E);
    fill_kernel    <<<tE, 256, 0, stream>>>(src, dst, cur, col, E);

    dim3 aggBlk(64, 4);
    int aggGrid = (N + 3) / 4;
    int gemmGrid = (N + BM - 1) / BM;

    gemm_kernel<<<gemmGrid, 256, 0, stream>>>(x, W1, hbuf, N);
    agg_kernel <<<aggGrid, aggBlk, 0, stream>>>((const float2*)hbuf, dis, rp, col,
                                                (const float2*)b1, (float2*)z1, N);
    gemm_kernel<<<gemmGrid, 256, 0, stream>>>(z1, W2, hbuf, N);
    agg_kernel <<<aggGrid, aggBlk, 0, stream>>>((const float2*)hbuf, dis, rp, col,
                                                (const float2*)b2, (float2*)d_out, N);
}